// Round 4
// baseline (1230.551 us; speedup 1.0000x reference)
//
#include <hip/hip_runtime.h>

// DIAGNOSTIC ROUND: exact R1 gather body, repeated `passes`=3 times inside one
// dispatch so our kernel out-lasts the harness's ~400us poison fills and shows
// up in the duration-sorted top-5 rocprof table (exposing FETCH/WRITE_SIZE).
// Passes are idempotent (same stores, same values) -> output stays correct.
// Runtime pass count (kernel arg) + memory barrier keep the compiler from
// collapsing the repeated passes.
//
// out[b, n, k, :] = features[b, topk_indices[b, n, k], :]
// B=32, N=4096, K=20, F=64, fp32.

constexpr int B = 32, N = 4096, K = 20, F = 64;
constexpr unsigned TOTAL_ROWS = (unsigned)B * N * K;          // 2,621,440
constexpr unsigned VEC_PER_ROW = F / 4;                       // 16 float4 per row
constexpr unsigned TOTAL_VEC = TOTAL_ROWS * VEC_PER_ROW;      // 41,943,040
constexpr unsigned NK = (unsigned)N * K;                      // 81,920

__global__ __launch_bounds__(256) void gather_rows_kernel(
    const int* __restrict__ idx,      // [B, N, K]
    const float* __restrict__ feat,   // [B, N, F]
    float* __restrict__ out,          // [B, N, K, F]
    int passes)                       // runtime (=3): prevents pass-collapse
{
    const unsigned tid0 = blockIdx.x * blockDim.x + threadIdx.x;
    const unsigned stride = gridDim.x * blockDim.x;
    const float4* __restrict__ featv = reinterpret_cast<const float4*>(feat);
    float4* __restrict__ outv = reinterpret_cast<float4*>(out);

    for (int p = 0; p < passes; ++p) {
        for (unsigned i = tid0; i < TOTAL_VEC; i += stride) {
            unsigned row = i >> 4;          // output row in [0, B*N*K)
            unsigned v   = i & 15u;         // float4 slot within the row
            unsigned b   = row / NK;        // batch (magic multiply)
            int id       = idx[row];        // 16 lanes share this dword
            unsigned src = (b * (unsigned)N + (unsigned)id) * VEC_PER_ROW + v;
            outv[i] = featv[src];
        }
        __threadfence();                    // keep passes ordered/alive
    }
}

extern "C" void kernel_launch(void* const* d_in, const int* in_sizes, int n_in,
                              void* d_out, int out_size, void* d_ws, size_t ws_size,
                              hipStream_t stream) {
    const int*   idx  = (const int*)d_in[0];    // topk_indices [B,N,K] int32
    const float* feat = (const float*)d_in[1];  // features [B,N,F] fp32
    float*       out  = (float*)d_out;          // [B,N,K,F] fp32

    gather_rows_kernel<<<2048, 256, 0, stream>>>(idx, feat, out, 3);
}

// Round 5
// 207.653 us; speedup vs baseline: 5.9260x; 5.9260x over previous
//
#include <hip/hip_runtime.h>

// out[b, n, k, :] = features[b, topk_indices[b, n, k], :]
// B=32, N=4096, K=20, F=64, fp32.
// R4 diagnostic: per pass WRITE=671MB (exact), FETCH~148MB -> reads are
// cache-resident; limiter is per-thread memory-level parallelism, not BW.
// R5: same mapping as the 187us R1 kernel, but compile-time loop + unroll 4
// so 4 independent idx->feat->store chains are in flight per thread.

constexpr int B = 32, N = 4096, K = 20, F = 64;
constexpr unsigned TOTAL_ROWS = (unsigned)B * N * K;          // 2,621,440
constexpr unsigned VEC_PER_ROW = F / 4;                       // 16 float4 per row
constexpr unsigned TOTAL_VEC = TOTAL_ROWS * VEC_PER_ROW;      // 41,943,040
constexpr unsigned NK = (unsigned)N * K;                      // 81,920

constexpr unsigned BLOCK = 256;
constexpr unsigned GRID = 2048;                               // 8192 waves = 32/CU, fully resident
constexpr unsigned THREADS = GRID * BLOCK;                    // 524,288
constexpr unsigned ITERS = TOTAL_VEC / THREADS;               // exactly 80
static_assert(ITERS * THREADS == TOTAL_VEC, "exact tiling");

__global__ __launch_bounds__(BLOCK) void gather_rows_kernel(
    const int* __restrict__ idx,      // [B, N, K]
    const float* __restrict__ feat,   // [B, N, F]
    float* __restrict__ out)          // [B, N, K, F]
{
    unsigned i = blockIdx.x * BLOCK + threadIdx.x;
    const float4* __restrict__ featv = reinterpret_cast<const float4*>(feat);
    float4* __restrict__ outv = reinterpret_cast<float4*>(out);

#pragma unroll 4
    for (unsigned j = 0; j < ITERS; ++j, i += THREADS) {
        unsigned row = i >> 4;          // output row in [0, B*N*K)
        unsigned v   = i & 15u;         // float4 slot within the row
        unsigned b   = row / NK;        // batch (magic multiply)
        int id       = idx[row];        // 16 lanes share this dword (L1 broadcast)
        unsigned src = (b * (unsigned)N + (unsigned)id) * VEC_PER_ROW + v;
        outv[i] = featv[src];
    }
}

extern "C" void kernel_launch(void* const* d_in, const int* in_sizes, int n_in,
                              void* d_out, int out_size, void* d_ws, size_t ws_size,
                              hipStream_t stream) {
    const int*   idx  = (const int*)d_in[0];    // topk_indices [B,N,K] int32
    const float* feat = (const float*)d_in[1];  // features [B,N,F] fp32
    float*       out  = (float*)d_out;          // [B,N,K,F] fp32

    gather_rows_kernel<<<GRID, BLOCK, 0, stream>>>(idx, feat, out);
}

// Round 6
// 186.211 us; speedup vs baseline: 6.6084x; 1.1152x over previous
//
#include <hip/hip_runtime.h>

// out[b, n, k, :] = features[b, topk_indices[b, n, k], :]
// B=32, N=4096, K=20, F=64, fp32.
//
// R4 diag: WRITE=671MB exact, FETCH=148MB (ideal 44MB). Logical feature reads
// are 671MB but per-XCD L2 is 4MB vs a 33.5MB scattered working set -> reads
// served by L3/HBM where they contend with the write stream.
// R6: batch<->XCD affinity. XCD x (= blockIdx&7 under round-robin dispatch)
// handles batches {x, x+8, x+16, x+24}, one batch phase at a time
// (grid 8192 ~= 4x resident capacity so phases serialize). Per-XCD live
// feature slab = 1MB -> L2-resident gather reads.

constexpr int B = 32, N = 4096, K = 20, F = 64;
constexpr unsigned NK = (unsigned)N * K;                      // 81,920 rows/batch
constexpr unsigned F4_PER_FEAT_BATCH = (unsigned)N * F / 4;   // 65,536 float4
constexpr unsigned F4_PER_BATCH = NK * (F / 4);               // 1,310,720 float4 out/batch

constexpr unsigned BLOCK = 256;
constexpr unsigned CHUNKS_PER_BATCH = 256;                    // blocks per batch
constexpr unsigned GRID = (unsigned)B * CHUNKS_PER_BATCH;     // 8192 blocks
constexpr unsigned F4_PER_CHUNK = F4_PER_BATCH / CHUNKS_PER_BATCH;  // 5120
constexpr unsigned ITERS = F4_PER_CHUNK / BLOCK;              // 20
static_assert(ITERS * BLOCK * CHUNKS_PER_BATCH == F4_PER_BATCH, "exact tiling");

__global__ __launch_bounds__(BLOCK) void gather_rows_kernel(
    const int* __restrict__ idx,      // [B, N, K]
    const float* __restrict__ feat,   // [B, N, F]
    float* __restrict__ out)          // [B, N, K, F]
{
    // XCD-affine decomposition: xcd = blockIdx&7 (round-robin dispatch),
    // seq = temporal order within that XCD's block stream.
    const unsigned xcd = blockIdx.x & 7u;
    const unsigned seq = blockIdx.x >> 3;            // [0, 1024)
    const unsigned b   = xcd + 8u * (seq >> 8);      // batch [0,32): 4 per XCD, phased
    const unsigned c   = seq & 255u;                 // chunk within batch [0,256)

    const float4* __restrict__ featv = reinterpret_cast<const float4*>(feat);
    float4* __restrict__ outv = reinterpret_cast<float4*>(out);

    const int* __restrict__ idxb = idx + b * NK;
    const unsigned featbase = b * F4_PER_FEAT_BATCH;
    const unsigned outbase  = b * F4_PER_BATCH;

#pragma unroll 1
    for (unsigned j = 0; j < ITERS; ++j) {
        unsigned il  = c * F4_PER_CHUNK + j * BLOCK + threadIdx.x; // f4 idx within batch
        unsigned row = il >> 4;          // row within batch [0, N*K)
        unsigned v   = il & 15u;         // float4 slot within the 64-float row
        int id       = idxb[row];        // 16 lanes share this dword
        outv[outbase + il] = featv[featbase + ((unsigned)id << 4) + v];
    }
}

extern "C" void kernel_launch(void* const* d_in, const int* in_sizes, int n_in,
                              void* d_out, int out_size, void* d_ws, size_t ws_size,
                              hipStream_t stream) {
    const int*   idx  = (const int*)d_in[0];    // topk_indices [B,N,K] int32
    const float* feat = (const float*)d_in[1];  // features [B,N,F] fp32
    float*       out  = (float*)d_out;          // [B,N,K,F] fp32

    gather_rows_kernel<<<GRID, BLOCK, 0, stream>>>(idx, feat, out);
}